// Round 2
// baseline (1123.641 us; speedup 1.0000x reference)
//
#include <hip/hip_runtime.h>

#define S_ 512
#define H_ 768
#define E_ 1024
#define L_ 50
#define NSPAN 5075
#define K3H 2304
#define CH 16

// ---------------- edge binning by label ----------------
__global__ void k_bin(const int* __restrict__ lbl, int* __restrict__ loff,
                      int* __restrict__ esort) {
  __shared__ int cnt[L_], cur[L_];
  int t = threadIdx.x;
  if (t < L_) cnt[t] = 0;
  __syncthreads();
  for (int e = t; e < E_; e += 256) atomicAdd(&cnt[lbl[e]], 1);
  __syncthreads();
  if (t == 0) {
    int s = 0;
    for (int l = 0; l < L_; ++l) { loff[l] = s; cur[l] = s; s += cnt[l]; }
    loff[L_] = s;
  }
  __syncthreads();
  for (int e = t; e < E_; e += 256) {
    int sl = atomicAdd(&cur[lbl[e]], 1);
    esort[sl] = e;
  }
}

// ---------------- span index tables ----------------
__global__ void k_spans(int* __restrict__ st, int* __restrict__ en) {
  int i = blockIdx.x * 64 + threadIdx.x;
  if (i >= S_) return;
  int cnt = min(10, S_ - i);
  int base;
  if (i <= 503) base = 10 * i;
  else { base = 5030; for (int q = 503; q < i; ++q) base += (S_ - q); }
  for (int k = 0; k < cnt; ++k) { st[base + k] = i; en[base + k] = i + k; }
}

// ---------------- grouped GCN matvec + scatter ----------------
__global__ __launch_bounds__(256) void k_gcn(
    const float* __restrict__ hidden, const float* __restrict__ gW,
    const float* __restrict__ gb, const int* __restrict__ esrc,
    const int* __restrict__ etgt, const int* __restrict__ loff,
    const int* __restrict__ esort, float* __restrict__ gout) {
  int l = blockIdx.x, by = blockIdx.y;
  int t = threadIdx.x;
  int o0 = loff[l], ne = loff[l + 1] - o0;
  __shared__ float xs[CH][H_];
  __shared__ int tgt_s[CH];
  const float* Wl = gW + (size_t)l * H_ * H_;
  int j0 = t, j1 = t + 256, j2 = t + 512;
  float bb0 = gb[l * H_ + j0], bb1 = gb[l * H_ + j1], bb2 = gb[l * H_ + j2];

  for (int c0 = by * CH; c0 < ne; c0 += 2 * CH) {
    int nc = min(CH, ne - c0);
    __syncthreads();
    for (int r = 0; r < nc; ++r) {
      int e = esort[o0 + c0 + r];
      int src = esrc[e];
      for (int h = t; h < H_; h += 256) xs[r][h] = hidden[src * H_ + h];
    }
    if (t < nc) tgt_s[t] = etgt[esort[o0 + c0 + t]];
    __syncthreads();

    float acc[CH][3];
#pragma unroll
    for (int e = 0; e < CH; ++e) { acc[e][0] = 0.f; acc[e][1] = 0.f; acc[e][2] = 0.f; }

    for (int i = 0; i < H_; i += 4) {
      float4 xv[CH];
#pragma unroll
      for (int e = 0; e < CH; ++e) xv[e] = *(const float4*)&xs[e][i];
#pragma unroll
      for (int u = 0; u < 4; ++u) {
        float w0 = Wl[(size_t)(i + u) * H_ + j0];
        float w1 = Wl[(size_t)(i + u) * H_ + j1];
        float w2 = Wl[(size_t)(i + u) * H_ + j2];
#pragma unroll
        for (int e = 0; e < CH; ++e) {
          float x = (&xv[e].x)[u];
          acc[e][0] = fmaf(x, w0, acc[e][0]);
          acc[e][1] = fmaf(x, w1, acc[e][1]);
          acc[e][2] = fmaf(x, w2, acc[e][2]);
        }
      }
    }
    for (int e = 0; e < nc; ++e) {
      int tg = tgt_s[e];
      atomicAdd(&gout[(size_t)tg * H_ + j0], acc[e][0] + bb0);
      atomicAdd(&gout[(size_t)tg * H_ + j1], acc[e][1] + bb1);
      atomicAdd(&gout[(size_t)tg * H_ + j2], acc[e][2] + bb2);
    }
  }
}

// ---------------- emb = hidden + relu(gcn), token scores ----------------
__global__ void k_emb(const float* __restrict__ hidden, const float* __restrict__ gout,
                      const float* __restrict__ aw, float* __restrict__ emb,
                      float* __restrict__ tsc) {
  int p = blockIdx.x, t = threadIdx.x;
  float dot = 0.f;
#pragma unroll
  for (int c = 0; c < 3; ++c) {
    int h = t + c * 256;
    float g = gout[(size_t)p * H_ + h];
    float v = hidden[(size_t)p * H_ + h] + fmaxf(g, 0.f);
    emb[(size_t)p * H_ + h] = v;
    dot += v * aw[h];
  }
#pragma unroll
  for (int off = 32; off; off >>= 1) dot += __shfl_down(dot, off);
  __shared__ float red[4];
  if ((t & 63) == 0) red[t >> 6] = dot;
  __syncthreads();
  if (t == 0) tsc[p] = red[0] + red[1] + red[2] + red[3];
}

// ---------------- span attention (10-tap weighted gather) ----------------
__global__ void k_attn(const float* __restrict__ emb, const float* __restrict__ tsc,
                       const int* __restrict__ st, const int* __restrict__ en,
                       float* __restrict__ aout) {
  int n = blockIdx.x, t = threadIdx.x;
  __shared__ float wts[10];
  __shared__ int sh[2];
  if (t == 0) {
    int s = st[n], len = en[n] - s + 1;
    sh[0] = s; sh[1] = len;
    float mx = -1e30f;
    for (int w = 0; w < len; ++w) mx = fmaxf(mx, tsc[s + w]);
    float sum = 0.f;
    for (int w = 0; w < len; ++w) { float p = __expf(tsc[s + w] - mx); wts[w] = p; sum += p; }
    float inv = 1.f / sum;
    for (int w = 0; w < len; ++w) wts[w] *= inv;
  }
  __syncthreads();
  int s = sh[0], len = sh[1];
#pragma unroll
  for (int c = 0; c < 3; ++c) {
    int h = t + c * 256;
    float a = 0.f;
    for (int w = 0; w < len; ++w) a = fmaf(wts[w], emb[(size_t)(s + w) * H_ + h], a);
    aout[(size_t)n * H_ + h] = a;
  }
}

// ---------------- fused big GEMM: relu(span_vec@W1+b1)@W2 (+b2) ----------------
// A (5075 x 2304) gathered on the fly: [emb[start] | emb[end] | attn_out]
// BM=128, BN=128, BK=16, 256 threads, 8x8 per thread. Epilogue fuses the
// W2 dot (relu -> *W2 -> shfl reduce -> atomicAdd to out).
__global__ __launch_bounds__(256) void k_gemm(
    const float* __restrict__ emb, const float* __restrict__ aout,
    const int* __restrict__ st, const int* __restrict__ en,
    const float* __restrict__ W1, const float* __restrict__ b1,
    const float* __restrict__ W2, const float* __restrict__ b2,
    float* __restrict__ out) {
  __shared__ float As[16][132];  // [kk][row], pad 132 keeps 16B alignment
  __shared__ float Bs[16][128];  // [kk][col]
  int t = threadIdx.x;
  int tx = t & 15, ty = t >> 4;
  int n0 = blockIdx.x * 128;
  int c0 = blockIdx.y * 128;

  int arow = t >> 1;           // each A row loaded by 2 threads
  int an = n0 + arow;
  bool valid = an < NSPAN;
  int sIdx = valid ? st[an] : 0;
  int eIdx = valid ? en[an] : 0;
  int koff = (t & 1) * 8;      // this thread's 8 k's within the BK=16 block

  const float* bp0 = W1 + (size_t)ty * K3H + c0 + tx * 8;

  float acc[8][8];
#pragma unroll
  for (int r = 0; r < 8; ++r)
#pragma unroll
    for (int c = 0; c < 8; ++c) acc[r][c] = 0.f;

  for (int k0 = 0; k0 < K3H; k0 += 16) {
    // gather A: segment boundaries (768, 1536) are BK-aligned
    const float* ap;
    if (k0 < H_)            ap = emb  + (size_t)sIdx * H_ + k0 + koff;
    else if (k0 < 2 * H_)   ap = emb  + (size_t)eIdx * H_ + (k0 - H_) + koff;
    else                    ap = aout + (size_t)an   * H_ + (k0 - 2 * H_) + koff;
    float4 a0, a1;
    if (valid) { a0 = *(const float4*)ap; a1 = *(const float4*)(ap + 4); }
    else { a0 = make_float4(0.f, 0.f, 0.f, 0.f); a1 = a0; }
    const float* bp = bp0 + (size_t)k0 * K3H;
    float4 bv0 = *(const float4*)bp;
    float4 bv1 = *(const float4*)(bp + 4);

    __syncthreads();
    As[koff + 0][arow] = a0.x; As[koff + 1][arow] = a0.y;
    As[koff + 2][arow] = a0.z; As[koff + 3][arow] = a0.w;
    As[koff + 4][arow] = a1.x; As[koff + 5][arow] = a1.y;
    As[koff + 6][arow] = a1.z; As[koff + 7][arow] = a1.w;
    *(float4*)&Bs[ty][tx * 8] = bv0;
    *(float4*)&Bs[ty][tx * 8 + 4] = bv1;
    __syncthreads();

#pragma unroll
    for (int kk = 0; kk < 16; ++kk) {
      float4 a0v = *(const float4*)&As[kk][ty * 8];
      float4 a1v = *(const float4*)&As[kk][ty * 8 + 4];
      float4 b0v = *(const float4*)&Bs[kk][tx * 8];
      float4 b1vv = *(const float4*)&Bs[kk][tx * 8 + 4];
      float ar[8] = {a0v.x, a0v.y, a0v.z, a0v.w, a1v.x, a1v.y, a1v.z, a1v.w};
      float br[8] = {b0v.x, b0v.y, b0v.z, b0v.w, b1vv.x, b1vv.y, b1vv.z, b1vv.w};
#pragma unroll
      for (int r = 0; r < 8; ++r)
#pragma unroll
        for (int c = 0; c < 8; ++c)
          acc[r][c] = fmaf(ar[r], br[c], acc[r][c]);
    }
  }

  // epilogue: relu(acc + b1) * W2, reduce 128 cols -> atomicAdd
  float b1v[8], w2v[8];
#pragma unroll
  for (int c = 0; c < 8; ++c) {
    b1v[c] = b1[c0 + tx * 8 + c];
    w2v[c] = W2[c0 + tx * 8 + c];
  }
  float bias2 = (blockIdx.y == 0) ? b2[0] : 0.f;
#pragma unroll
  for (int r = 0; r < 8; ++r) {
    float p = 0.f;
#pragma unroll
    for (int c = 0; c < 8; ++c) {
      float hd = acc[r][c] + b1v[c];
      hd = fmaxf(hd, 0.f);
      p = fmaf(hd, w2v[c], p);
    }
    p += __shfl_xor(p, 1);
    p += __shfl_xor(p, 2);
    p += __shfl_xor(p, 4);
    p += __shfl_xor(p, 8);
    int n = n0 + ty * 8 + r;
    if (tx == 0 && n < NSPAN) atomicAdd(&out[n], p + bias2);
  }
}

extern "C" void kernel_launch(void* const* d_in, const int* in_sizes, int n_in,
                              void* d_out, int out_size, void* d_ws, size_t ws_size,
                              hipStream_t stream) {
  const float* hidden = (const float*)d_in[0];
  const float* gW     = (const float*)d_in[1];
  const float* gb     = (const float*)d_in[2];
  const float* aw     = (const float*)d_in[3];
  // d_in[4] = attn_b: softmax-invariant, unused
  const float* W1     = (const float*)d_in[5];
  const float* b1     = (const float*)d_in[6];
  const float* W2     = (const float*)d_in[7];
  const float* b2     = (const float*)d_in[8];
  const int* esrc     = (const int*)d_in[9];
  const int* etgt     = (const int*)d_in[10];
  const int* elbl     = (const int*)d_in[11];
  float* out = (float*)d_out;

  float* ws   = (float*)d_ws;
  float* gout = ws;                         // S*H
  float* emb  = gout + S_ * H_;             // S*H
  float* tsc  = emb + S_ * H_;              // 512
  float* aout = tsc + 512;                  // NSPAN*H
  int* st     = (int*)(aout + (size_t)NSPAN * H_);
  int* en     = st + 5088;
  int* loff   = en + 5088;
  int* esort  = loff + 64;

  hipMemsetAsync(gout, 0, S_ * H_ * sizeof(float), stream);
  hipMemsetAsync(d_out, 0, (size_t)out_size * sizeof(float), stream);
  k_bin<<<1, 256, 0, stream>>>(elbl, loff, esort);
  k_spans<<<8, 64, 0, stream>>>(st, en);
  k_gcn<<<dim3(L_, 2), 256, 0, stream>>>(hidden, gW, gb, esrc, etgt, loff, esort, gout);
  k_emb<<<S_, 256, 0, stream>>>(hidden, gout, aw, emb, tsc);
  k_attn<<<NSPAN, 256, 0, stream>>>(emb, tsc, st, en, aout);
  k_gemm<<<dim3(40, 18), 256, 0, stream>>>(emb, aout, st, en, W1, b1, W2, b2, out);
}

// Round 4
// 550.966 us; speedup vs baseline: 2.0394x; 2.0394x over previous
//
#include <hip/hip_runtime.h>

#define S_ 512
#define H_ 768
#define E_ 1024
#define L_ 50
#define NSPAN 5075
#define K3H 2304
#define CH 16

typedef __attribute__((ext_vector_type(8))) short short8;
typedef __attribute__((ext_vector_type(4))) float f32x4;

__device__ __forceinline__ ushort f2bf(float f) {
  uint u = __float_as_uint(f);
  u += 0x7fffu + ((u >> 16) & 1u);   // RNE
  return (ushort)(u >> 16);
}

// ---------------- edge binning by label ----------------
__global__ void k_bin(const int* __restrict__ lbl, int* __restrict__ loff,
                      int* __restrict__ esort) {
  __shared__ int cnt[L_], cur[L_];
  int t = threadIdx.x;
  if (t < L_) cnt[t] = 0;
  __syncthreads();
  for (int e = t; e < E_; e += 256) atomicAdd(&cnt[lbl[e]], 1);
  __syncthreads();
  if (t == 0) {
    int s = 0;
    for (int l = 0; l < L_; ++l) { loff[l] = s; cur[l] = s; s += cnt[l]; }
    loff[L_] = s;
  }
  __syncthreads();
  for (int e = t; e < E_; e += 256) {
    int sl = atomicAdd(&cur[lbl[e]], 1);
    esort[sl] = e;
  }
}

// ---------------- span index tables ----------------
__global__ void k_spans(int* __restrict__ st, int* __restrict__ en) {
  int i = blockIdx.x * 64 + threadIdx.x;
  if (i >= S_) return;
  int cnt = min(10, S_ - i);
  int base;
  if (i <= 503) base = 10 * i;
  else { base = 5030; for (int q = 503; q < i; ++q) base += (S_ - q); }
  for (int k = 0; k < cnt; ++k) { st[base + k] = i; en[base + k] = i + k; }
}

// ---------------- grouped GCN matvec + scatter ----------------
__global__ __launch_bounds__(256) void k_gcn(
    const float* __restrict__ hidden, const float* __restrict__ gW,
    const float* __restrict__ gb, const int* __restrict__ esrc,
    const int* __restrict__ etgt, const int* __restrict__ loff,
    const int* __restrict__ esort, float* __restrict__ gout) {
  int l = blockIdx.x, by = blockIdx.y;
  int t = threadIdx.x;
  int o0 = loff[l], ne = loff[l + 1] - o0;
  __shared__ float xs[CH][H_];
  __shared__ int tgt_s[CH];
  const float* Wl = gW + (size_t)l * H_ * H_;
  int j0 = t, j1 = t + 256, j2 = t + 512;
  float bb0 = gb[l * H_ + j0], bb1 = gb[l * H_ + j1], bb2 = gb[l * H_ + j2];

  for (int c0 = by * CH; c0 < ne; c0 += 2 * CH) {
    int nc = min(CH, ne - c0);
    __syncthreads();
    for (int r = 0; r < nc; ++r) {
      int e = esort[o0 + c0 + r];
      int src = esrc[e];
      for (int h = t; h < H_; h += 256) xs[r][h] = hidden[src * H_ + h];
    }
    if (t < nc) tgt_s[t] = etgt[esort[o0 + c0 + t]];
    __syncthreads();

    float acc[CH][3];
#pragma unroll
    for (int e = 0; e < CH; ++e) { acc[e][0] = 0.f; acc[e][1] = 0.f; acc[e][2] = 0.f; }

    for (int i = 0; i < H_; i += 4) {
      float4 xv[CH];
#pragma unroll
      for (int e = 0; e < CH; ++e) xv[e] = *(const float4*)&xs[e][i];
#pragma unroll
      for (int u = 0; u < 4; ++u) {
        float w0 = Wl[(size_t)(i + u) * H_ + j0];
        float w1 = Wl[(size_t)(i + u) * H_ + j1];
        float w2 = Wl[(size_t)(i + u) * H_ + j2];
#pragma unroll
        for (int e = 0; e < CH; ++e) {
          float x = (&xv[e].x)[u];
          acc[e][0] = fmaf(x, w0, acc[e][0]);
          acc[e][1] = fmaf(x, w1, acc[e][1]);
          acc[e][2] = fmaf(x, w2, acc[e][2]);
        }
      }
    }
    for (int e = 0; e < nc; ++e) {
      int tg = tgt_s[e];
      atomicAdd(&gout[(size_t)tg * H_ + j0], acc[e][0] + bb0);
      atomicAdd(&gout[(size_t)tg * H_ + j1], acc[e][1] + bb1);
      atomicAdd(&gout[(size_t)tg * H_ + j2], acc[e][2] + bb2);
    }
  }
}

// ---------------- emb = hidden + relu(gcn), token scores, bf16 copy ----------------
__global__ void k_emb(const float* __restrict__ hidden, const float* __restrict__ gout,
                      const float* __restrict__ aw, float* __restrict__ emb,
                      ushort* __restrict__ emb_b, float* __restrict__ tsc) {
  int p = blockIdx.x, t = threadIdx.x;
  float dot = 0.f;
#pragma unroll
  for (int c = 0; c < 3; ++c) {
    int h = t + c * 256;
    float g = gout[(size_t)p * H_ + h];
    float v = hidden[(size_t)p * H_ + h] + fmaxf(g, 0.f);
    emb[(size_t)p * H_ + h] = v;
    emb_b[(size_t)p * H_ + h] = f2bf(v);
    dot += v * aw[h];
  }
#pragma unroll
  for (int off = 32; off; off >>= 1) dot += __shfl_down(dot, off);
  __shared__ float red[4];
  if ((t & 63) == 0) red[t >> 6] = dot;
  __syncthreads();
  if (t == 0) tsc[p] = red[0] + red[1] + red[2] + red[3];
}

// ---------------- span attention (10-tap weighted gather) -> bf16 ----------------
__global__ void k_attn(const float* __restrict__ emb, const float* __restrict__ tsc,
                       const int* __restrict__ st, const int* __restrict__ en,
                       ushort* __restrict__ aout_b) {
  int n = blockIdx.x, t = threadIdx.x;
  __shared__ float wts[10];
  __shared__ int sh[2];
  if (t == 0) {
    int s = st[n], len = en[n] - s + 1;
    sh[0] = s; sh[1] = len;
    float mx = -1e30f;
    for (int w = 0; w < len; ++w) mx = fmaxf(mx, tsc[s + w]);
    float sum = 0.f;
    for (int w = 0; w < len; ++w) { float p = __expf(tsc[s + w] - mx); wts[w] = p; sum += p; }
    float inv = 1.f / sum;
    for (int w = 0; w < len; ++w) wts[w] *= inv;
  }
  __syncthreads();
  int s = sh[0], len = sh[1];
#pragma unroll
  for (int c = 0; c < 3; ++c) {
    int h = t + c * 256;
    float a = 0.f;
    for (int w = 0; w < len; ++w) a = fmaf(wts[w], emb[(size_t)(s + w) * H_ + h], a);
    aout_b[(size_t)n * H_ + h] = f2bf(a);
  }
}

// ---------------- pack W1 -> bf16 in GEMM LDS order ----------------
// Bp[nblk][kstep][kgrp][col][e] = W1[kstep*64+kgrp*8+e][nblk*128+col]
__global__ void k_bpack(const float* __restrict__ W1, ushort* __restrict__ Bp) {
  int nblk = blockIdx.x, kstep = blockIdx.y;
  int t = threadIdx.x;
  int col = t & 127, kg2 = t >> 7;
  const float* src = W1 + (size_t)(kstep * 64) * K3H + nblk * 128 + col;
  ushort* dst = Bp + (size_t)(nblk * 36 + kstep) * 8192;
#pragma unroll
  for (int g = 0; g < 4; ++g) {
    int kgrp = kg2 * 4 + g;
    short8 pv;
#pragma unroll
    for (int e = 0; e < 8; ++e)
      pv[e] = (short)f2bf(src[(size_t)(kgrp * 8 + e) * K3H]);
    *(short8*)(dst + (size_t)kgrp * 1024 + col * 8) = pv;
  }
}

// ---------------- MFMA GEMM: relu(span_vec@W1+b1)@W2 (+b2) ----------------
// BM=BN=128, BK=64, 4 waves (2x2), each wave 64x64 out via 4x4 16x16 frags.
// A gathered per-lane (global_load_lds, linear LDS dest); B linear from Bp.
// LDS layout [kgrp 8][row/col 128][8 bf16] -> conflict-free ds_read_b128.
__global__ __launch_bounds__(256) void k_gemm2(
    const ushort* __restrict__ emb_b, const ushort* __restrict__ aout_b,
    const int* __restrict__ st, const int* __restrict__ en,
    const ushort* __restrict__ Bp, const float* __restrict__ b1,
    const float* __restrict__ W2, const float* __restrict__ b2,
    float* __restrict__ out) {
  __shared__ short As[8192];
  __shared__ short Bs[8192];
  int t = threadIdx.x;
  int l = t & 63, w = t >> 6;
  int n0 = blockIdx.x * 128;   // span rows
  int c0 = blockIdx.y * 128;   // hidden cols
  int wr = w >> 1, wc = w & 1;

  // staging source pointers (per thread: row = t&127, kgrp base = (t>>7)*8)
  int srow = t & 127;
  int span = min(n0 + srow, NSPAN - 1);
  int kgh = (t >> 7) * 8;
  const ushort* ps = emb_b + (size_t)st[span] * H_ + kgh;
  const ushort* pe = emb_b + (size_t)en[span] * H_ + kgh;
  const ushort* pa = aout_b + (size_t)span * H_ + kgh;
  const ushort* pb = Bp + (size_t)blockIdx.y * 36 * 8192 + t * 8;
  short* ldsA = &As[w * 512];
  short* ldsB = &Bs[w * 512];

  f32x4 acc[4][4];
#pragma unroll
  for (int m = 0; m < 4; ++m)
#pragma unroll
    for (int n = 0; n < 4; ++n) acc[m][n] = (f32x4){0.f, 0.f, 0.f, 0.f};

  for (int kstep = 0; kstep < 36; ++kstep) {
    int seg = (kstep >= 24) ? 2 : (kstep >= 12) ? 1 : 0;
    int k0m = (kstep - seg * 12) * 64;
    const ushort* pA = (seg == 0 ? ps : (seg == 1 ? pe : pa)) + k0m;
    const ushort* pB = pb + (size_t)kstep * 8192;

    __syncthreads();
#pragma unroll
    for (int i = 0; i < 4; ++i) {
      __builtin_amdgcn_global_load_lds((const uint*)(pA + i * 16),
                                       (uint*)(ldsA + i * 2048), 16, 0, 0);
      __builtin_amdgcn_global_load_lds((const uint*)(pB + i * 2048),
                                       (uint*)(ldsB + i * 2048), 16, 0, 0);
    }
    __syncthreads();

#pragma unroll
    for (int ks = 0; ks < 2; ++ks) {
      int kg = ks * 4 + (l >> 4);
      int rbase = (kg * 128 + wr * 64 + (l & 15)) * 8;
      int cbase = (kg * 128 + wc * 64 + (l & 15)) * 8;
      short8 af[4], bfr[4];
#pragma unroll
      for (int m = 0; m < 4; ++m) af[m] = *(const short8*)&As[rbase + m * 128];
#pragma unroll
      for (int n = 0; n < 4; ++n) bfr[n] = *(const short8*)&Bs[cbase + n * 128];
#pragma unroll
      for (int m = 0; m < 4; ++m)
#pragma unroll
        for (int n = 0; n < 4; ++n)
          acc[m][n] = __builtin_amdgcn_mfma_f32_16x16x32_bf16(af[m], bfr[n], acc[m][n], 0, 0, 0);
    }
  }

  // epilogue: relu(acc+b1)*W2, reduce over 16 cols, atomicAdd per row
  float b1v[4], w2v[4];
#pragma unroll
  for (int n = 0; n < 4; ++n) {
    int col = c0 + wc * 64 + n * 16 + (l & 15);
    b1v[n] = b1[col];
    w2v[n] = W2[col];
  }
  float bias2 = (blockIdx.y == 0 && wc == 0) ? b2[0] : 0.f;
#pragma unroll
  for (int m = 0; m < 4; ++m)
#pragma unroll
    for (int reg = 0; reg < 4; ++reg) {
      float p = 0.f;
#pragma unroll
      for (int n = 0; n < 4; ++n) {
        float hd = acc[m][n][reg] + b1v[n];
        p = fmaf(fmaxf(hd, 0.f), w2v[n], p);
      }
      p += __shfl_xor(p, 1);
      p += __shfl_xor(p, 2);
      p += __shfl_xor(p, 4);
      p += __shfl_xor(p, 8);
      int row = n0 + wr * 64 + m * 16 + ((l >> 4) << 2) + reg;
      if ((l & 15) == 0 && row < NSPAN) atomicAdd(&out[row], p + bias2);
    }
}

extern "C" void kernel_launch(void* const* d_in, const int* in_sizes, int n_in,
                              void* d_out, int out_size, void* d_ws, size_t ws_size,
                              hipStream_t stream) {
  const float* hidden = (const float*)d_in[0];
  const float* gW     = (const float*)d_in[1];
  const float* gb     = (const float*)d_in[2];
  const float* aw     = (const float*)d_in[3];
  // d_in[4] = attn_b: softmax-invariant, unused
  const float* W1     = (const float*)d_in[5];
  const float* b1     = (const float*)d_in[6];
  const float* W2     = (const float*)d_in[7];
  const float* b2     = (const float*)d_in[8];
  const int* esrc     = (const int*)d_in[9];
  const int* etgt     = (const int*)d_in[10];
  const int* elbl     = (const int*)d_in[11];
  float* out = (float*)d_out;

  float* ws    = (float*)d_ws;
  float* gout  = ws;                          // S*H f32
  float* emb   = gout + S_ * H_;              // S*H f32
  float* tsc   = emb + S_ * H_;               // 512 f32
  ushort* emb_b  = (ushort*)(tsc + 512);      // S*H bf16
  ushort* aout_b = emb_b + (size_t)S_ * H_;   // NSPAN*H bf16
  ushort* Bp     = aout_b + (size_t)NSPAN * H_; // K3H*K3H bf16 (packed)
  int* st    = (int*)(Bp + (size_t)K3H * K3H);
  int* en    = st + 5088;
  int* loff  = en + 5088;
  int* esort = loff + 64;

  hipMemsetAsync(gout, 0, S_ * H_ * sizeof(float), stream);
  hipMemsetAsync(d_out, 0, (size_t)out_size * sizeof(float), stream);
  k_bin<<<1, 256, 0, stream>>>(elbl, loff, esort);
  k_spans<<<8, 64, 0, stream>>>(st, en);
  k_bpack<<<dim3(18, 36), 256, 0, stream>>>(W1, Bp);
  k_gcn<<<dim3(L_, 2), 256, 0, stream>>>(hidden, gW, gb, esrc, etgt, loff, esort, gout);
  k_emb<<<S_, 256, 0, stream>>>(hidden, gout, aw, emb, emb_b, tsc);
  k_attn<<<NSPAN, 256, 0, stream>>>(emb, tsc, st, en, aout_b);
  k_gemm2<<<dim3(40, 18), 256, 0, stream>>>(emb_b, aout_b, st, en, Bp, b1, W2, b2, out);
}

// Round 5
// 363.472 us; speedup vs baseline: 3.0914x; 1.5158x over previous
//
#include <hip/hip_runtime.h>

#define S_ 512
#define H_ 768
#define E_ 1024
#define L_ 50
#define NSPAN 5075
#define K3H 2304

typedef __attribute__((ext_vector_type(8))) short short8;
typedef __attribute__((ext_vector_type(4))) float f32x4;

__device__ __forceinline__ ushort f2bf(float f) {
  uint u = __float_as_uint(f);
  u += 0x7fffu + ((u >> 16) & 1u);   // RNE
  return (ushort)(u >> 16);
}

// ---------------- edge binning by label ----------------
__global__ void k_bin(const int* __restrict__ lbl, int* __restrict__ loff,
                      int* __restrict__ esort) {
  __shared__ int cnt[L_], cur[L_];
  int t = threadIdx.x;
  if (t < L_) cnt[t] = 0;
  __syncthreads();
  for (int e = t; e < E_; e += 256) atomicAdd(&cnt[lbl[e]], 1);
  __syncthreads();
  if (t == 0) {
    int s = 0;
    for (int l = 0; l < L_; ++l) { loff[l] = s; cur[l] = s; s += cnt[l]; }
    loff[L_] = s;
  }
  __syncthreads();
  for (int e = t; e < E_; e += 256) {
    int sl = atomicAdd(&cur[lbl[e]], 1);
    esort[sl] = e;
  }
}

// ---------------- span index tables ----------------
__global__ void k_spans(int* __restrict__ st, int* __restrict__ en) {
  int i = blockIdx.x * 64 + threadIdx.x;
  if (i >= S_) return;
  int cnt = min(10, S_ - i);
  int base;
  if (i <= 503) base = 10 * i;
  else { base = 5030; for (int q = 503; q < i; ++q) base += (S_ - q); }
  for (int k = 0; k < cnt; ++k) { st[base + k] = i; en[base + k] = i + k; }
}

// ---------------- GCN: grid (label, kblk, cblk), 450 blocks ----------------
// Each block: 256x256 W slice streamed once (coalesced), <=32 edges staged in
// LDS (broadcast reads), 32 register partials, atomicAdd scatter into gout.
// k-split is legal: gout is an atomic accumulator; bias added by kb==0 only.
__global__ __launch_bounds__(256) void k_gcn2(
    const float* __restrict__ hidden, const float* __restrict__ gW,
    const float* __restrict__ gb, const int* __restrict__ esrc,
    const int* __restrict__ etgt, const int* __restrict__ loff,
    const int* __restrict__ esort, float* __restrict__ gout) {
  int l = blockIdx.x, kb = blockIdx.y, cb = blockIdx.z;
  int t = threadIdx.x;
  int o0 = loff[l], ne = loff[l + 1] - o0;
  if (ne == 0) return;
  __shared__ float xs[32][256];
  __shared__ int tgt_s[32];
  int j = cb * 256 + t;
  const float* Wl = gW + (size_t)l * H_ * H_ + (size_t)(kb * 256) * H_ + j;
  float bb = (kb == 0) ? gb[l * H_ + j] : 0.f;

  for (int c0 = 0; c0 < ne; c0 += 32) {
    int nc = min(32, ne - c0);
    __syncthreads();
    for (int e = 0; e < nc; ++e) {
      int ed = esort[o0 + c0 + e];
      xs[e][t] = hidden[(size_t)esrc[ed] * H_ + kb * 256 + t];
    }
    for (int e = nc; e < 32; ++e) xs[e][t] = 0.f;
    if (t < nc) tgt_s[t] = etgt[esort[o0 + c0 + t]];
    __syncthreads();

    float acc[32];
#pragma unroll
    for (int e = 0; e < 32; ++e) acc[e] = 0.f;

#pragma unroll 2
    for (int i0 = 0; i0 < 256; i0 += 4) {
      float w0 = Wl[(size_t)(i0 + 0) * H_];
      float w1 = Wl[(size_t)(i0 + 1) * H_];
      float w2 = Wl[(size_t)(i0 + 2) * H_];
      float w3 = Wl[(size_t)(i0 + 3) * H_];
#pragma unroll
      for (int e = 0; e < 32; ++e) {
        float4 xv = *(const float4*)&xs[e][i0];
        acc[e] = fmaf(xv.x, w0, acc[e]);
        acc[e] = fmaf(xv.y, w1, acc[e]);
        acc[e] = fmaf(xv.z, w2, acc[e]);
        acc[e] = fmaf(xv.w, w3, acc[e]);
      }
    }
    for (int e = 0; e < nc; ++e)
      atomicAdd(&gout[(size_t)tgt_s[e] * H_ + j], acc[e] + bb);
  }
}

// ---------------- emb = hidden + relu(gcn), token scores, bf16 copy ----------------
__global__ void k_emb(const float* __restrict__ hidden, const float* __restrict__ gout,
                      const float* __restrict__ aw, float* __restrict__ emb,
                      ushort* __restrict__ emb_b, float* __restrict__ tsc) {
  int p = blockIdx.x, t = threadIdx.x;
  float dot = 0.f;
#pragma unroll
  for (int c = 0; c < 3; ++c) {
    int h = t + c * 256;
    float g = gout[(size_t)p * H_ + h];
    float v = hidden[(size_t)p * H_ + h] + fmaxf(g, 0.f);
    emb[(size_t)p * H_ + h] = v;
    emb_b[(size_t)p * H_ + h] = f2bf(v);
    dot += v * aw[h];
  }
#pragma unroll
  for (int off = 32; off; off >>= 1) dot += __shfl_down(dot, off);
  __shared__ float red[4];
  if ((t & 63) == 0) red[t >> 6] = dot;
  __syncthreads();
  if (t == 0) tsc[p] = red[0] + red[1] + red[2] + red[3];
}

// ---------------- span attention (10-tap weighted gather) -> bf16 ----------------
__global__ void k_attn(const float* __restrict__ emb, const float* __restrict__ tsc,
                       const int* __restrict__ st, const int* __restrict__ en,
                       ushort* __restrict__ aout_b) {
  int n = blockIdx.x, t = threadIdx.x;
  __shared__ float wts[10];
  __shared__ int sh[2];
  if (t == 0) {
    int s = st[n], len = en[n] - s + 1;
    sh[0] = s; sh[1] = len;
    float mx = -1e30f;
    for (int w = 0; w < len; ++w) mx = fmaxf(mx, tsc[s + w]);
    float sum = 0.f;
    for (int w = 0; w < len; ++w) { float p = __expf(tsc[s + w] - mx); wts[w] = p; sum += p; }
    float inv = 1.f / sum;
    for (int w = 0; w < len; ++w) wts[w] *= inv;
  }
  __syncthreads();
  int s = sh[0], len = sh[1];
#pragma unroll
  for (int c = 0; c < 3; ++c) {
    int h = t + c * 256;
    float a = 0.f;
    for (int w = 0; w < len; ++w) a = fmaf(wts[w], emb[(size_t)(s + w) * H_ + h], a);
    aout_b[(size_t)n * H_ + h] = f2bf(a);
  }
}

// ---------------- pack W1 -> bf16 in GEMM LDS order ----------------
// Bp[nblk][kstep][kgrp][col][e] = W1[kstep*64+kgrp*8+e][nblk*128+col]
__global__ void k_bpack(const float* __restrict__ W1, ushort* __restrict__ Bp) {
  int nblk = blockIdx.x, kstep = blockIdx.y;
  int t = threadIdx.x;
  int col = t & 127, kg2 = t >> 7;
  const float* src = W1 + (size_t)(kstep * 64) * K3H + nblk * 128 + col;
  ushort* dst = Bp + (size_t)(nblk * 36 + kstep) * 8192;
#pragma unroll
  for (int g = 0; g < 4; ++g) {
    int kgrp = kg2 * 4 + g;
    short8 pv;
#pragma unroll
    for (int e = 0; e < 8; ++e)
      pv[e] = (short)f2bf(src[(size_t)(kgrp * 8 + e) * K3H]);
    *(short8*)(dst + (size_t)kgrp * 1024 + col * 8) = pv;
  }
}

// ---------------- MFMA GEMM: relu(span_vec@W1+b1)@W2 (+b2) ----------------
// BM=BN=128, BK=64, 4 waves (2x2), each wave 64x64 out via 4x4 16x16 frags.
// A gathered per-lane (global_load_lds, linear LDS dest); B linear from Bp.
// LDS layout [kgrp 8][row/col 128][8 bf16] -> conflict-free ds_read_b128.
__global__ __launch_bounds__(256) void k_gemm2(
    const ushort* __restrict__ emb_b, const ushort* __restrict__ aout_b,
    const int* __restrict__ st, const int* __restrict__ en,
    const ushort* __restrict__ Bp, const float* __restrict__ b1,
    const float* __restrict__ W2, const float* __restrict__ b2,
    float* __restrict__ out) {
  __shared__ short As[8192];
  __shared__ short Bs[8192];
  int t = threadIdx.x;
  int l = t & 63, w = t >> 6;
  int n0 = blockIdx.x * 128;   // span rows
  int c0 = blockIdx.y * 128;   // hidden cols
  int wr = w >> 1, wc = w & 1;

  // staging source pointers (per thread: row = t&127, kgrp base = (t>>7)*8)
  int srow = t & 127;
  int span = min(n0 + srow, NSPAN - 1);
  int kgh = (t >> 7) * 8;
  const ushort* ps = emb_b + (size_t)st[span] * H_ + kgh;
  const ushort* pe = emb_b + (size_t)en[span] * H_ + kgh;
  const ushort* pa = aout_b + (size_t)span * H_ + kgh;
  const ushort* pb = Bp + (size_t)blockIdx.y * 36 * 8192 + t * 8;
  short* ldsA = &As[w * 512];
  short* ldsB = &Bs[w * 512];

  f32x4 acc[4][4];
#pragma unroll
  for (int m = 0; m < 4; ++m)
#pragma unroll
    for (int n = 0; n < 4; ++n) acc[m][n] = (f32x4){0.f, 0.f, 0.f, 0.f};

  for (int kstep = 0; kstep < 36; ++kstep) {
    int seg = (kstep >= 24) ? 2 : (kstep >= 12) ? 1 : 0;
    int k0m = (kstep - seg * 12) * 64;
    const ushort* pA = (seg == 0 ? ps : (seg == 1 ? pe : pa)) + k0m;
    const ushort* pB = pb + (size_t)kstep * 8192;

    __syncthreads();
#pragma unroll
    for (int i = 0; i < 4; ++i) {
      __builtin_amdgcn_global_load_lds((const uint*)(pA + i * 16),
                                       (uint*)(ldsA + i * 2048), 16, 0, 0);
      __builtin_amdgcn_global_load_lds((const uint*)(pB + i * 2048),
                                       (uint*)(ldsB + i * 2048), 16, 0, 0);
    }
    __syncthreads();

#pragma unroll
    for (int ks = 0; ks < 2; ++ks) {
      int kg = ks * 4 + (l >> 4);
      int rbase = (kg * 128 + wr * 64 + (l & 15)) * 8;
      int cbase = (kg * 128 + wc * 64 + (l & 15)) * 8;
      short8 af[4], bfr[4];
#pragma unroll
      for (int m = 0; m < 4; ++m) af[m] = *(const short8*)&As[rbase + m * 128];
#pragma unroll
      for (int n = 0; n < 4; ++n) bfr[n] = *(const short8*)&Bs[cbase + n * 128];
#pragma unroll
      for (int m = 0; m < 4; ++m)
#pragma unroll
        for (int n = 0; n < 4; ++n)
          acc[m][n] = __builtin_amdgcn_mfma_f32_16x16x32_bf16(af[m], bfr[n], acc[m][n], 0, 0, 0);
    }
  }

  // epilogue: relu(acc+b1)*W2, reduce over 16 cols, atomicAdd per row
  float b1v[4], w2v[4];
#pragma unroll
  for (int n = 0; n < 4; ++n) {
    int col = c0 + wc * 64 + n * 16 + (l & 15);
    b1v[n] = b1[col];
    w2v[n] = W2[col];
  }
  float bias2 = (blockIdx.y == 0 && wc == 0) ? b2[0] : 0.f;
#pragma unroll
  for (int m = 0; m < 4; ++m)
#pragma unroll
    for (int reg = 0; reg < 4; ++reg) {
      float p = 0.f;
#pragma unroll
      for (int n = 0; n < 4; ++n) {
        float hd = acc[m][n][reg] + b1v[n];
        p = fmaf(fmaxf(hd, 0.f), w2v[n], p);
      }
      p += __shfl_xor(p, 1);
      p += __shfl_xor(p, 2);
      p += __shfl_xor(p, 4);
      p += __shfl_xor(p, 8);
      int row = n0 + wr * 64 + m * 16 + ((l >> 4) << 2) + reg;
      if ((l & 15) == 0 && row < NSPAN) atomicAdd(&out[row], p + bias2);
    }
}

extern "C" void kernel_launch(void* const* d_in, const int* in_sizes, int n_in,
                              void* d_out, int out_size, void* d_ws, size_t ws_size,
                              hipStream_t stream) {
  const float* hidden = (const float*)d_in[0];
  const float* gW     = (const float*)d_in[1];
  const float* gb     = (const float*)d_in[2];
  const float* aw     = (const float*)d_in[3];
  // d_in[4] = attn_b: softmax-invariant, unused
  const float* W1     = (const float*)d_in[5];
  const float* b1     = (const float*)d_in[6];
  const float* W2     = (const float*)d_in[7];
  const float* b2     = (const float*)d_in[8];
  const int* esrc     = (const int*)d_in[9];
  const int* etgt     = (const int*)d_in[10];
  const int* elbl     = (const int*)d_in[11];
  float* out = (float*)d_out;

  float* ws    = (float*)d_ws;
  float* gout  = ws;                          // S*H f32
  float* emb   = gout + S_ * H_;              // S*H f32
  float* tsc   = emb + S_ * H_;               // 512 f32
  ushort* emb_b  = (ushort*)(tsc + 512);      // S*H bf16
  ushort* aout_b = emb_b + (size_t)S_ * H_;   // NSPAN*H bf16
  ushort* Bp     = aout_b + (size_t)NSPAN * H_; // K3H*K3H bf16 (packed)
  int* st    = (int*)(Bp + (size_t)K3H * K3H);
  int* en    = st + 5088;
  int* loff  = en + 5088;
  int* esort = loff + 64;

  hipMemsetAsync(gout, 0, S_ * H_ * sizeof(float), stream);
  hipMemsetAsync(d_out, 0, (size_t)out_size * sizeof(float), stream);
  k_bin<<<1, 256, 0, stream>>>(elbl, loff, esort);
  k_spans<<<8, 64, 0, stream>>>(st, en);
  k_bpack<<<dim3(18, 36), 256, 0, stream>>>(W1, Bp);
  k_gcn2<<<dim3(L_, 3, 3), 256, 0, stream>>>(hidden, gW, gb, esrc, etgt, loff, esort, gout);
  k_emb<<<S_, 256, 0, stream>>>(hidden, gout, aw, emb, emb_b, tsc);
  k_attn<<<NSPAN, 256, 0, stream>>>(emb, tsc, st, en, aout_b);
  k_gemm2<<<dim3(40, 18), 256, 0, stream>>>(emb_b, aout_b, st, en, Bp, b1, W2, b2, out);
}

// Round 6
// 297.541 us; speedup vs baseline: 3.7764x; 1.2216x over previous
//
#include <hip/hip_runtime.h>

#define S_ 512
#define H_ 768
#define E_ 1024
#define L_ 50
#define NSPAN 5075
#define K3H 2304

typedef __attribute__((ext_vector_type(8))) short short8;
typedef __attribute__((ext_vector_type(4))) float f32x4;

__device__ __forceinline__ ushort f2bf(float f) {
  uint u = __float_as_uint(f);
  u += 0x7fffu + ((u >> 16) & 1u);   // RNE
  return (ushort)(u >> 16);
}
__device__ __forceinline__ float bf2f(ushort u) {
  return __uint_as_float(((uint)u) << 16);
}

// ---------------- edge binning by label ----------------
__global__ void k_bin(const int* __restrict__ lbl, int* __restrict__ loff,
                      int* __restrict__ esort) {
  __shared__ int cnt[L_], cur[L_];
  int t = threadIdx.x;
  if (t < L_) cnt[t] = 0;
  __syncthreads();
  for (int e = t; e < E_; e += 256) atomicAdd(&cnt[lbl[e]], 1);
  __syncthreads();
  if (t == 0) {
    int s = 0;
    for (int l = 0; l < L_; ++l) { loff[l] = s; cur[l] = s; s += cnt[l]; }
    loff[L_] = s;
  }
  __syncthreads();
  for (int e = t; e < E_; e += 256) {
    int sl = atomicAdd(&cur[lbl[e]], 1);
    esort[sl] = e;
  }
}

// ---------------- GCN via bf16 MFMA ----------------
// grid (label, cb=6): per block 128 cols, full K=768, m-tiles of 32 edges.
// W converted fp32->bf16 inline during LDS staging (no pack pass).
// LDS: xs[kg8][m32][8], Ws[kg8][col128][8] -> same frag algebra as k_gemm2.
__global__ __launch_bounds__(256) void k_gcn3(
    const float* __restrict__ hidden, const float* __restrict__ gW,
    const float* __restrict__ gb, const int* __restrict__ esrc,
    const int* __restrict__ etgt, const int* __restrict__ loff,
    const int* __restrict__ esort, float* __restrict__ gout) {
  int l = blockIdx.x, cb = blockIdx.y;
  int t = threadIdx.x;
  int o0 = loff[l], ne = loff[l + 1] - o0;
  if (ne == 0) return;
  __shared__ short xs[2048];
  __shared__ short Ws[8192];
  __shared__ int src_s[32], tgt_s[32];
  int lane = t & 63, w = t >> 6;
  int c0 = cb * 128;
  int j = t & 127, hoct = t >> 7;
  const float* Wbase = gW + (size_t)l * H_ * H_ + c0 + j;
  int sm = t & 31, soct = t >> 5;

  for (int m0 = 0; m0 < ne; m0 += 32) {
    int nc = min(32, ne - m0);
    __syncthreads();
    if (t < 32) {
      int ed = esort[o0 + m0 + ((t < nc) ? t : 0)];
      src_s[t] = esrc[ed];
      tgt_s[t] = etgt[ed];
    }
    __syncthreads();
    f32x4 acc[2][2];
#pragma unroll
    for (int mf = 0; mf < 2; ++mf)
#pragma unroll
      for (int nf = 0; nf < 2; ++nf) acc[mf][nf] = (f32x4){0.f, 0.f, 0.f, 0.f};
    const float* xrow = hidden + (size_t)src_s[sm] * H_ + soct * 8;
    bool xvalid = sm < nc;

    for (int k0 = 0; k0 < H_; k0 += 64) {
      __syncthreads();
      short8 xv = {0, 0, 0, 0, 0, 0, 0, 0};
      if (xvalid) {
        float4 x0 = *(const float4*)(xrow + k0);
        float4 x1 = *(const float4*)(xrow + k0 + 4);
        xv[0] = (short)f2bf(x0.x); xv[1] = (short)f2bf(x0.y);
        xv[2] = (short)f2bf(x0.z); xv[3] = (short)f2bf(x0.w);
        xv[4] = (short)f2bf(x1.x); xv[5] = (short)f2bf(x1.y);
        xv[6] = (short)f2bf(x1.z); xv[7] = (short)f2bf(x1.w);
      }
      *(short8*)&xs[(soct * 32 + sm) * 8] = xv;
#pragma unroll
      for (int p = 0; p < 4; ++p) {
        int io = p * 2 + hoct;
        const float* wp = Wbase + (size_t)(k0 + io * 8) * H_;
        short8 wv;
#pragma unroll
        for (int q = 0; q < 8; ++q) wv[q] = (short)f2bf(wp[(size_t)q * H_]);
        *(short8*)&Ws[(io * 128 + j) * 8] = wv;
      }
      __syncthreads();
#pragma unroll
      for (int ks = 0; ks < 2; ++ks) {
        int kg = ks * 4 + (lane >> 4);
        short8 af[2], bfv[2];
#pragma unroll
        for (int mf = 0; mf < 2; ++mf)
          af[mf] = *(const short8*)&xs[(kg * 32 + mf * 16 + (lane & 15)) * 8];
#pragma unroll
        for (int nf = 0; nf < 2; ++nf)
          bfv[nf] = *(const short8*)&Ws[(kg * 128 + w * 32 + nf * 16 + (lane & 15)) * 8];
#pragma unroll
        for (int mf = 0; mf < 2; ++mf)
#pragma unroll
          for (int nf = 0; nf < 2; ++nf)
            acc[mf][nf] = __builtin_amdgcn_mfma_f32_16x16x32_bf16(af[mf], bfv[nf], acc[mf][nf], 0, 0, 0);
      }
    }
    // epilogue: scatter msgs + bias into gout (atomic)
#pragma unroll
    for (int mf = 0; mf < 2; ++mf) {
      int e0 = mf * 16 + (lane >> 4) * 4;
#pragma unroll
      for (int nf = 0; nf < 2; ++nf) {
        int col = c0 + w * 32 + nf * 16 + (lane & 15);
        float bias = gb[l * H_ + col];
#pragma unroll
        for (int reg = 0; reg < 4; ++reg) {
          int e = e0 + reg;
          if (e < nc)
            atomicAdd(&gout[(size_t)tgt_s[e] * H_ + col], acc[mf][nf][reg] + bias);
        }
      }
    }
  }
}

// ---------------- emb_b = bf16(hidden + relu(gcn)), token scores ----------------
__global__ void k_emb(const float* __restrict__ hidden, const float* __restrict__ gout,
                      const float* __restrict__ aw, ushort* __restrict__ emb_b,
                      float* __restrict__ tsc) {
  int p = blockIdx.x, t = threadIdx.x;
  float dot = 0.f;
#pragma unroll
  for (int c = 0; c < 3; ++c) {
    int h = t + c * 256;
    float g = gout[(size_t)p * H_ + h];
    float v = hidden[(size_t)p * H_ + h] + fmaxf(g, 0.f);
    emb_b[(size_t)p * H_ + h] = f2bf(v);
    dot += v * aw[h];
  }
#pragma unroll
  for (int off = 32; off; off >>= 1) dot += __shfl_down(dot, off);
  __shared__ float red[4];
  if ((t & 63) == 0) red[t >> 6] = dot;
  __syncthreads();
  if (t == 0) tsc[p] = red[0] + red[1] + red[2] + red[3];
}

// ---------------- P[seg] = emb_b @ W1[seg*768:(seg+1)*768, :]  (bf16 out) ----
// grid (4 mblk, 18 nblk, 3 seg); 128x128 tile, BK=64; A via global_load_lds
// (gemm2-verified mapping); B = inline fp32->bf16 convert of W1.
__global__ __launch_bounds__(256) void k_pgemm(
    const ushort* __restrict__ emb_b, const float* __restrict__ W1,
    ushort* __restrict__ P) {
  __shared__ short As[8192];
  __shared__ short Bs[8192];
  int t = threadIdx.x;
  int lane = t & 63, w = t >> 6;
  int m0 = blockIdx.x * 128, c0 = blockIdx.y * 128, seg = blockIdx.z;
  int wr = w >> 1, wc = w & 1;
  const ushort* pa = emb_b + (size_t)(m0 + (t & 127)) * H_ + (t >> 7) * 8;
  short* ldsA = &As[w * 512];
  int j = t & 127, hoct = t >> 7;
  const float* Wb = W1 + (size_t)(seg * H_) * K3H + c0 + j;

  f32x4 acc[4][4];
#pragma unroll
  for (int mf = 0; mf < 4; ++mf)
#pragma unroll
    for (int nf = 0; nf < 4; ++nf) acc[mf][nf] = (f32x4){0.f, 0.f, 0.f, 0.f};

  for (int k0 = 0; k0 < H_; k0 += 64) {
    __syncthreads();
#pragma unroll
    for (int i = 0; i < 4; ++i)
      __builtin_amdgcn_global_load_lds((const uint*)(pa + k0 + i * 16),
                                       (uint*)(ldsA + i * 2048), 16, 0, 0);
#pragma unroll
    for (int p = 0; p < 4; ++p) {
      int io = p * 2 + hoct;
      const float* wp = Wb + (size_t)(k0 + io * 8) * K3H;
      short8 wv;
#pragma unroll
      for (int q = 0; q < 8; ++q) wv[q] = (short)f2bf(wp[(size_t)q * K3H]);
      *(short8*)&Bs[(io * 128 + j) * 8] = wv;
    }
    __syncthreads();
#pragma unroll
    for (int ks = 0; ks < 2; ++ks) {
      int kg = ks * 4 + (lane >> 4);
      int rbase = (kg * 128 + wr * 64 + (lane & 15)) * 8;
      int cbase = (kg * 128 + wc * 64 + (lane & 15)) * 8;
      short8 af[4], bfv[4];
#pragma unroll
      for (int mf = 0; mf < 4; ++mf) af[mf] = *(const short8*)&As[rbase + mf * 128];
#pragma unroll
      for (int nf = 0; nf < 4; ++nf) bfv[nf] = *(const short8*)&Bs[cbase + nf * 128];
#pragma unroll
      for (int mf = 0; mf < 4; ++mf)
#pragma unroll
        for (int nf = 0; nf < 4; ++nf)
          acc[mf][nf] = __builtin_amdgcn_mfma_f32_16x16x32_bf16(af[mf], bfv[nf], acc[mf][nf], 0, 0, 0);
    }
  }
  ushort* Pseg = P + (size_t)seg * S_ * K3H;
#pragma unroll
  for (int mf = 0; mf < 4; ++mf)
#pragma unroll
    for (int nf = 0; nf < 4; ++nf) {
      int col = c0 + wc * 64 + nf * 16 + (lane & 15);
#pragma unroll
      for (int reg = 0; reg < 4; ++reg) {
        int m = m0 + wr * 64 + mf * 16 + ((lane >> 4) << 2) + reg;
        Pseg[(size_t)m * K3H + col] = f2bf(acc[mf][nf][reg]);
      }
    }
}

// ---------------- fused span scoring ----------------
// grid (128 start-groups of 4, 3 col-tiles of 768).
// out[n] = relu(P1[st] + P2[en] + sum_w wts*P3[st+w] + b1) . W2  (+b2)
// Per block: stage 13 rows x 768 cols of P1,P2,P3 (bf16) in LDS; wave w owns
// start i0+w; spans len 1..maxlen; 64 lanes x 12 cols; wave-reduce; atomicAdd.
__global__ __launch_bounds__(256) void k_span(
    const ushort* __restrict__ P, const float* __restrict__ tsc,
    const float* __restrict__ b1, const float* __restrict__ W2,
    const float* __restrict__ b2, float* __restrict__ out) {
  __shared__ short Ps[3 * 13 * 768];
  __shared__ float tss[13];
  int t = threadIdx.x;
  int i0 = blockIdx.x * 4;
  int ct = blockIdx.y, cc0 = ct * 768;
  // stage: 3 mats x 13 rows x 96 short8 = 3744 vector loads
  for (int idx = t; idx < 3744; idx += 256) {
    int mat = idx / 1248;
    int rem = idx - mat * 1248;
    int r = rem / 96, part = rem - r * 96;
    int row = min(i0 + r, S_ - 1);
    short8 v = *(const short8*)(P + (size_t)mat * S_ * K3H + (size_t)row * K3H + cc0 + part * 8);
    *(short8*)&Ps[idx * 8] = v;
  }
  if (t < 13) tss[t] = tsc[min(i0 + t, S_ - 1)];
  __syncthreads();

  int w = t >> 6, lane = t & 63;
  int i = i0 + w;                       // this wave's start (always < 512)
  int maxlen = min(10, S_ - i);
  int base = (i <= 502) ? 10 * i : NSPAN - (S_ - i) * (S_ + 1 - i) / 2;

  float p1r[12], b1r[12], w2r[12];
#pragma unroll
  for (int jj = 0; jj < 12; ++jj) {
    int c = lane + 64 * jj;
    p1r[jj] = bf2f((ushort)Ps[0 * 9984 + w * 768 + c]);
    b1r[jj] = b1[cc0 + c];
    w2r[jj] = W2[cc0 + c];
  }
  float bias2 = (ct == 0) ? b2[0] : 0.f;

  for (int L = 1; L <= maxlen; ++L) {
    // softmax weights over tss[w .. w+L-1] (computed redundantly per lane)
    float wts[10];
    float mx = -1e30f;
    for (int q = 0; q < L; ++q) mx = fmaxf(mx, tss[w + q]);
    float s = 0.f;
    for (int q = 0; q < L; ++q) { wts[q] = __expf(tss[w + q] - mx); s += wts[q]; }
    float inv = 1.f / s;

    float part = 0.f;
#pragma unroll
    for (int jj = 0; jj < 12; ++jj) {
      int c = lane + 64 * jj;
      float a = 0.f;
      for (int q = 0; q < L; ++q)
        a = fmaf(wts[q], bf2f((ushort)Ps[2 * 9984 + (w + q) * 768 + c]), a);
      float v = p1r[jj] + bf2f((ushort)Ps[1 * 9984 + (w + L - 1) * 768 + c]) + b1r[jj] + a * inv;
      part = fmaf(fmaxf(v, 0.f), w2r[jj], part);
    }
#pragma unroll
    for (int off = 32; off; off >>= 1) part += __shfl_xor(part, off);
    if (lane == 0) atomicAdd(&out[base + L - 1], part + bias2);
  }
}

extern "C" void kernel_launch(void* const* d_in, const int* in_sizes, int n_in,
                              void* d_out, int out_size, void* d_ws, size_t ws_size,
                              hipStream_t stream) {
  const float* hidden = (const float*)d_in[0];
  const float* gW     = (const float*)d_in[1];
  const float* gb     = (const float*)d_in[2];
  const float* aw     = (const float*)d_in[3];
  // d_in[4] = attn_b: softmax-invariant, unused
  const float* W1     = (const float*)d_in[5];
  const float* b1     = (const float*)d_in[6];
  const float* W2     = (const float*)d_in[7];
  const float* b2     = (const float*)d_in[8];
  const int* esrc     = (const int*)d_in[9];
  const int* etgt     = (const int*)d_in[10];
  const int* elbl     = (const int*)d_in[11];
  float* out = (float*)d_out;

  float* ws     = (float*)d_ws;
  float* gout   = ws;                           // S*H f32
  float* tsc    = gout + S_ * H_;               // 512 f32
  ushort* emb_b = (ushort*)(tsc + 512);         // S*H bf16
  ushort* P     = emb_b + (size_t)S_ * H_;      // 3*S*K3H bf16
  int* loff     = (int*)(P + (size_t)3 * S_ * K3H);
  int* esort    = loff + 64;

  hipMemsetAsync(gout, 0, S_ * H_ * sizeof(float), stream);
  hipMemsetAsync(d_out, 0, (size_t)out_size * sizeof(float), stream);
  k_bin<<<1, 256, 0, stream>>>(elbl, loff, esort);
  k_gcn3<<<dim3(L_, 6), 256, 0, stream>>>(hidden, gW, gb, esrc, etgt, loff, esort, gout);
  k_emb<<<S_, 256, 0, stream>>>(hidden, gout, aw, emb_b, tsc);
  k_pgemm<<<dim3(4, 18, 3), 256, 0, stream>>>(emb_b, W1, P);
  k_span<<<dim3(128, 3), 256, 0, stream>>>(P, tsc, b1, W2, b2, out);
}

// Round 9
// 263.869 us; speedup vs baseline: 4.2583x; 1.1276x over previous
//
#include <hip/hip_runtime.h>

#define S_ 512
#define H_ 768
#define E_ 1024
#define L_ 50
#define NSPAN 5075
#define K3H 2304

typedef __attribute__((ext_vector_type(8))) short short8;
typedef __attribute__((ext_vector_type(4))) float f32x4;

__device__ __forceinline__ ushort f2bf(float f) {
  uint u = __float_as_uint(f);
  u += 0x7fffu + ((u >> 16) & 1u);   // RNE
  return (ushort)(u >> 16);
}
__device__ __forceinline__ float bf2f(ushort u) {
  return __uint_as_float(((uint)u) << 16);
}

// ---------------- edge binning by label ----------------
__global__ void k_bin(const int* __restrict__ lbl, int* __restrict__ loff,
                      int* __restrict__ esort) {
  __shared__ int cnt[L_], cur[L_];
  int t = threadIdx.x;
  if (t < L_) cnt[t] = 0;
  __syncthreads();
  for (int e = t; e < E_; e += 256) atomicAdd(&cnt[lbl[e]], 1);
  __syncthreads();
  if (t == 0) {
    int s = 0;
    for (int l = 0; l < L_; ++l) { loff[l] = s; cur[l] = s; s += cnt[l]; }
    loff[L_] = s;
  }
  __syncthreads();
  for (int e = t; e < E_; e += 256) {
    int sl = atomicAdd(&cur[lbl[e]], 1);
    esort[sl] = e;
  }
}

// ---------------- pack W1 -> bf16 in GEMM LDS order (round-4 verified) ----
// Bp[nblk][kstep][kgrp][col][e] = W1[kstep*64+kgrp*8+e][nblk*128+col]
__global__ void k_bpack(const float* __restrict__ W1, ushort* __restrict__ Bp) {
  int nblk = blockIdx.x, kstep = blockIdx.y;
  int t = threadIdx.x;
  int col = t & 127, kg2 = t >> 7;
  const float* src = W1 + (size_t)(kstep * 64) * K3H + nblk * 128 + col;
  ushort* dst = Bp + (size_t)(nblk * 36 + kstep) * 8192;
#pragma unroll
  for (int g = 0; g < 4; ++g) {
    int kgrp = kg2 * 4 + g;
    short8 pv;
#pragma unroll
    for (int e = 0; e < 8; ++e)
      pv[e] = (short)f2bf(src[(size_t)(kgrp * 8 + e) * K3H]);
    *(short8*)(dst + (size_t)kgrp * 1024 + col * 8) = pv;
  }
}

// ---------------- GCN via bf16 MFMA, k-split for parallelism ----------------
// grid (label, cb=6, kb=2): 600 blocks. Per block: 128 cols, 384 k, m-tiles 32.
__global__ __launch_bounds__(256) void k_gcn3(
    const float* __restrict__ hidden, const float* __restrict__ gW,
    const float* __restrict__ gb, const int* __restrict__ esrc,
    const int* __restrict__ etgt, const int* __restrict__ loff,
    const int* __restrict__ esort, float* __restrict__ gout) {
  int l = blockIdx.x, cb = blockIdx.y, kb = blockIdx.z;
  int t = threadIdx.x;
  int o0 = loff[l], ne = loff[l + 1] - o0;
  if (ne == 0) return;
  __shared__ short xs[2048];
  __shared__ short Ws[8192];
  __shared__ int src_s[32], tgt_s[32];
  int lane = t & 63, w = t >> 6;
  int c0 = cb * 128;
  int j = t & 127, hoct = t >> 7;
  const float* Wbase = gW + (size_t)l * H_ * H_ + c0 + j;
  int sm = t & 31, soct = t >> 5;
  int kbeg = kb * 384, kend = kbeg + 384;

  for (int m0 = 0; m0 < ne; m0 += 32) {
    int nc = min(32, ne - m0);
    __syncthreads();
    if (t < 32) {
      int ed = esort[o0 + m0 + ((t < nc) ? t : 0)];
      src_s[t] = esrc[ed];
      tgt_s[t] = etgt[ed];
    }
    __syncthreads();
    f32x4 acc[2][2];
#pragma unroll
    for (int mf = 0; mf < 2; ++mf)
#pragma unroll
      for (int nf = 0; nf < 2; ++nf) acc[mf][nf] = (f32x4){0.f, 0.f, 0.f, 0.f};
    const float* xrow = hidden + (size_t)src_s[sm] * H_ + soct * 8;
    bool xvalid = sm < nc;

    for (int k0 = kbeg; k0 < kend; k0 += 64) {
      __syncthreads();
      short8 xv = {0, 0, 0, 0, 0, 0, 0, 0};
      if (xvalid) {
        float4 x0 = *(const float4*)(xrow + k0);
        float4 x1 = *(const float4*)(xrow + k0 + 4);
        xv[0] = (short)f2bf(x0.x); xv[1] = (short)f2bf(x0.y);
        xv[2] = (short)f2bf(x0.z); xv[3] = (short)f2bf(x0.w);
        xv[4] = (short)f2bf(x1.x); xv[5] = (short)f2bf(x1.y);
        xv[6] = (short)f2bf(x1.z); xv[7] = (short)f2bf(x1.w);
      }
      *(short8*)&xs[(soct * 32 + sm) * 8] = xv;
#pragma unroll
      for (int p = 0; p < 4; ++p) {
        int io = p * 2 + hoct;
        const float* wp = Wbase + (size_t)(k0 + io * 8) * H_;
        short8 wv;
#pragma unroll
        for (int q = 0; q < 8; ++q) wv[q] = (short)f2bf(wp[(size_t)q * H_]);
        *(short8*)&Ws[(io * 128 + j) * 8] = wv;
      }
      __syncthreads();
#pragma unroll
      for (int ks = 0; ks < 2; ++ks) {
        int kg = ks * 4 + (lane >> 4);
        short8 af[2], bfv[2];
#pragma unroll
        for (int mf = 0; mf < 2; ++mf)
          af[mf] = *(const short8*)&xs[(kg * 32 + mf * 16 + (lane & 15)) * 8];
#pragma unroll
        for (int nf = 0; nf < 2; ++nf)
          bfv[nf] = *(const short8*)&Ws[(kg * 128 + w * 32 + nf * 16 + (lane & 15)) * 8];
#pragma unroll
        for (int mf = 0; mf < 2; ++mf)
#pragma unroll
          for (int nf = 0; nf < 2; ++nf)
            acc[mf][nf] = __builtin_amdgcn_mfma_f32_16x16x32_bf16(af[mf], bfv[nf], acc[mf][nf], 0, 0, 0);
      }
    }
#pragma unroll
    for (int mf = 0; mf < 2; ++mf) {
      int e0 = mf * 16 + (lane >> 4) * 4;
#pragma unroll
      for (int nf = 0; nf < 2; ++nf) {
        int col = c0 + w * 32 + nf * 16 + (lane & 15);
        float bias = (kb == 0) ? gb[l * H_ + col] : 0.f;
#pragma unroll
        for (int reg = 0; reg < 4; ++reg) {
          int e = e0 + reg;
          if (e < nc)
            atomicAdd(&gout[(size_t)tgt_s[e] * H_ + col], acc[mf][nf][reg] + bias);
        }
      }
    }
  }
}

// ---------------- emb_b = bf16(hidden + relu(gcn)), token scores ----------------
__global__ void k_emb(const float* __restrict__ hidden, const float* __restrict__ gout,
                      const float* __restrict__ aw, ushort* __restrict__ emb_b,
                      float* __restrict__ tsc) {
  int p = blockIdx.x, t = threadIdx.x;
  float dot = 0.f;
#pragma unroll
  for (int c = 0; c < 3; ++c) {
    int h = t + c * 256;
    float g = gout[(size_t)p * H_ + h];
    float v = hidden[(size_t)p * H_ + h] + fmaxf(g, 0.f);
    emb_b[(size_t)p * H_ + h] = f2bf(v);
    dot += v * aw[h];
  }
#pragma unroll
  for (int off = 32; off; off >>= 1) dot += __shfl_down(dot, off);
  __shared__ float red[4];
  if ((t & 63) == 0) red[t >> 6] = dot;
  __syncthreads();
  if (t == 0) tsc[p] = red[0] + red[1] + red[2] + red[3];
}

// ---------------- P[seg] = emb_b @ W1seg via packed Bp ----------------
// grid (8 mblk, 18 nblk, 3 seg) = 432 blocks; BM=64, BN=128, BK=64.
// 4 waves 2x2: wave tile 32x64 (acc[2][4]). A+B both via global_load_lds.
__global__ __launch_bounds__(256) void k_pgemm(
    const ushort* __restrict__ emb_b, const ushort* __restrict__ Bp,
    ushort* __restrict__ P) {
  __shared__ short As[4096];   // [kg8][row64][8]
  __shared__ short Bs[8192];   // [kg8][col128][8]
  int t = threadIdx.x;
  int lane = t & 63, w = t >> 6;
  int m0 = blockIdx.x * 64, c0 = blockIdx.y * 128, seg = blockIdx.z;
  int wr = w >> 1, wc = w & 1;
  const ushort* pa = emb_b + (size_t)(m0 + lane) * H_;
  const ushort* pb = Bp + ((size_t)blockIdx.y * 36 + seg * 12) * 8192 + t * 8;

  f32x4 acc[2][4];
#pragma unroll
  for (int mf = 0; mf < 2; ++mf)
#pragma unroll
    for (int nf = 0; nf < 4; ++nf) acc[mf][nf] = (f32x4){0.f, 0.f, 0.f, 0.f};

  for (int kk = 0; kk < 12; ++kk) {
    int k0 = kk * 64;
    __syncthreads();
#pragma unroll
    for (int i = 0; i < 2; ++i)
      __builtin_amdgcn_global_load_lds((const uint*)(pa + k0 + (w + i * 4) * 8),
                                       (uint*)&As[(w + i * 4) * 512], 16, 0, 0);
#pragma unroll
    for (int i = 0; i < 4; ++i)
      __builtin_amdgcn_global_load_lds((const uint*)(pb + (size_t)kk * 8192 + i * 2048),
                                       (uint*)&Bs[w * 512 + i * 2048], 16, 0, 0);
    __syncthreads();

#pragma unroll
    for (int ks = 0; ks < 2; ++ks) {
      int kg = ks * 4 + (lane >> 4);
      int rbase = (kg * 64 + wr * 32 + (lane & 15)) * 8;
      int cbase = (kg * 128 + wc * 64 + (lane & 15)) * 8;
      short8 af[2], bfv[4];
#pragma unroll
      for (int mf = 0; mf < 2; ++mf) af[mf] = *(const short8*)&As[rbase + mf * 128];
#pragma unroll
      for (int nf = 0; nf < 4; ++nf) bfv[nf] = *(const short8*)&Bs[cbase + nf * 128];
#pragma unroll
      for (int mf = 0; mf < 2; ++mf)
#pragma unroll
        for (int nf = 0; nf < 4; ++nf)
          acc[mf][nf] = __builtin_amdgcn_mfma_f32_16x16x32_bf16(af[mf], bfv[nf], acc[mf][nf], 0, 0, 0);
    }
  }
  ushort* Pseg = P + (size_t)seg * S_ * K3H;
#pragma unroll
  for (int mf = 0; mf < 2; ++mf)
#pragma unroll
    for (int nf = 0; nf < 4; ++nf) {
      int col = c0 + wc * 64 + nf * 16 + (lane & 15);
#pragma unroll
      for (int reg = 0; reg < 4; ++reg) {
        int m = m0 + wr * 32 + mf * 16 + ((lane >> 4) << 2) + reg;
        Pseg[(size_t)m * K3H + col] = f2bf(acc[mf][nf][reg]);
      }
    }
}

// ---------------- fused span scoring (online prefix softmax, all-static) ----
// grid (256 start-pairs, 6 col-tiles of 384). Wave: (start-local, col-half).
// out[n] = relu(P1[st]+P2[en]+A/S+b1).W2 (+b2), A/S = prefix softmax combine.
__global__ __launch_bounds__(256) void k_span(
    const ushort* __restrict__ P, const float* __restrict__ tsc,
    const float* __restrict__ b1, const float* __restrict__ W2,
    const float* __restrict__ b2, float* __restrict__ out) {
  __shared__ short Ps[3][11][384];
  __shared__ float tss[11];
  int t = threadIdx.x;
  int i0 = blockIdx.x * 2;
  int ct = blockIdx.y, cc0 = ct * 384;
  for (int idx = t; idx < 1584; idx += 256) {
    int mat = idx / 528;
    int rem = idx - mat * 528;
    int r = rem / 48, part = rem - r * 48;
    int row = min(i0 + r, S_ - 1);
    short8 v = *(const short8*)(P + ((size_t)mat * S_ + row) * K3H + cc0 + part * 8);
    *(short8*)&Ps[mat][r][part * 8] = v;
  }
  if (t < 11) tss[t] = tsc[min(i0 + t, S_ - 1)];
  __syncthreads();

  int w = t >> 6, lane = t & 63;
  int sl = w >> 1, ch = w & 1;
  int i = i0 + sl;
  int maxlen = min(10, S_ - i);
  int base = (i <= 502) ? 10 * i : NSPAN - (S_ - i) * (S_ + 1 - i) / 2;

  int ca = ch * 192 + lane, cb2 = ca + 64, cc2 = ca + 128;
  float p10 = bf2f((ushort)Ps[0][sl][ca]);
  float p11 = bf2f((ushort)Ps[0][sl][cb2]);
  float p12 = bf2f((ushort)Ps[0][sl][cc2]);
  float b10 = b1[cc0 + ca], b11 = b1[cc0 + cb2], b12 = b1[cc0 + cc2];
  float w20 = W2[cc0 + ca], w21 = W2[cc0 + cb2], w22 = W2[cc0 + cc2];
  float bias2 = (ct == 0 && ch == 0) ? b2[0] : 0.f;

  // window-global max (shift-invariant => identical softmax for every L)
  float mx = -1e30f;
#pragma unroll
  for (int q = 0; q < 10; ++q)
    if (q < maxlen) mx = fmaxf(mx, tss[sl + q]);
  float e[10];
#pragma unroll
  for (int q = 0; q < 10; ++q)
    e[q] = (q < maxlen) ? __expf(tss[sl + q] - mx) : 0.f;

  float A0 = 0.f, A1 = 0.f, A2 = 0.f, Ssum = 0.f;
#pragma unroll
  for (int L = 1; L <= 10; ++L) {
    if (L > maxlen) break;
    int r = sl + L - 1;
    float ee = e[L - 1];
    Ssum += ee;
    float inv = 1.f / Ssum;
    A0 = fmaf(ee, bf2f((ushort)Ps[2][r][ca]), A0);
    A1 = fmaf(ee, bf2f((ushort)Ps[2][r][cb2]), A1);
    A2 = fmaf(ee, bf2f((ushort)Ps[2][r][cc2]), A2);
    float v0 = p10 + bf2f((ushort)Ps[1][r][ca]) + b10 + A0 * inv;
    float v1 = p11 + bf2f((ushort)Ps[1][r][cb2]) + b11 + A1 * inv;
    float v2 = p12 + bf2f((ushort)Ps[1][r][cc2]) + b12 + A2 * inv;
    float part = fmaf(fmaxf(v0, 0.f), w20, 0.f);
    part = fmaf(fmaxf(v1, 0.f), w21, part);
    part = fmaf(fmaxf(v2, 0.f), w22, part);
#pragma unroll
    for (int off = 32; off; off >>= 1) part += __shfl_xor(part, off);
    if (lane == 0) atomicAdd(&out[base + L - 1], part + bias2);
  }
}

extern "C" void kernel_launch(void* const* d_in, const int* in_sizes, int n_in,
                              void* d_out, int out_size, void* d_ws, size_t ws_size,
                              hipStream_t stream) {
  const float* hidden = (const float*)d_in[0];
  const float* gW     = (const float*)d_in[1];
  const float* gb     = (const float*)d_in[2];
  const float* aw     = (const float*)d_in[3];
  // d_in[4] = attn_b: softmax-invariant, unused
  const float* W1     = (const float*)d_in[5];
  const float* b1     = (const float*)d_in[6];
  const float* W2     = (const float*)d_in[7];
  const float* b2     = (const float*)d_in[8];
  const int* esrc     = (const int*)d_in[9];
  const int* etgt     = (const int*)d_in[10];
  const int* elbl     = (const int*)d_in[11];
  float* out = (float*)d_out;

  float* ws     = (float*)d_ws;
  float* gout   = ws;                           // S*H f32
  float* tsc    = gout + S_ * H_;               // 512 f32
  ushort* emb_b = (ushort*)(tsc + 512);         // S*H bf16
  ushort* P     = emb_b + (size_t)S_ * H_;      // 3*S*K3H bf16
  ushort* Bp    = P + (size_t)3 * S_ * K3H;     // K3H*K3H bf16
  int* loff     = (int*)(Bp + (size_t)K3H * K3H);
  int* esort    = loff + 64;

  hipMemsetAsync(gout, 0, S_ * H_ * sizeof(float), stream);
  hipMemsetAsync(d_out, 0, (size_t)out_size * sizeof(float), stream);
  k_bin<<<1, 256, 0, stream>>>(elbl, loff, esort);
  k_bpack<<<dim3(18, 36), 256, 0, stream>>>(W1, Bp);
  k_gcn3<<<dim3(L_, 6, 2), 256, 0, stream>>>(hidden, gW, gb, esrc, etgt, loff, esort, gout);
  k_emb<<<S_, 256, 0, stream>>>(hidden, gout, aw, emb_b, tsc);
  k_pgemm<<<dim3(8, 18, 3), 256, 0, stream>>>(emb_b, Bp, P);
  k_span<<<dim3(256, 6), 256, 0, stream>>>(P, tsc, b1, W2, b2, out);
}